// Round 4
// baseline (19711.919 us; speedup 1.0000x reference)
//
#include <hip/hip_runtime.h>
#include <math.h>

// Paraphraser seq2seq: bi-LSTM encoder + attention decoder + fused vocab log-softmax.
// Shapes: S=40, B=32, T=40, E=256, H=512, V=50000. All fp32 except vocab GEMM (bf16 MFMA).
// Round 4: grid.sync measured ~50us -> removed. Recurrence runs as per-(dir,batch)
// independent persistent blocks (no inter-block sync at all). Vocab GEMM -> bf16 MFMA.

#define S_LEN 40
#define BATCH 32
#define EMB   256
#define HID   512
#define G4H   2048          // 4*H
#define NVOC  50000
#define NDEC  39            // T-1 decoder steps
#define NCHUNK 196          // ceil(50000/256)
#define MROWS 1248          // NDEC*BATCH real rows into vocab GEMM
#define MPAD  1280          // padded to 10 tiles of 128 rows

typedef __attribute__((ext_vector_type(8))) short short8v;
typedef __attribute__((ext_vector_type(4))) float f32x4;

__device__ __forceinline__ float sigf(float x) { return 1.f / (1.f + expf(-x)); }
__device__ __forceinline__ unsigned short f2bf(float x) {
  unsigned u = __float_as_uint(x);
  return (unsigned short)((u + 0x7fffu + ((u >> 16) & 1u)) >> 16);   // RNE
}

// ---------------- embedding gather ----------------
__global__ __launch_bounds__(256) void k_embed(
    const int* __restrict__ src_ids, const int* __restrict__ tgt_ids,
    const float* __restrict__ src_emb, const float* __restrict__ tgt_emb,
    float* __restrict__ src_e, float* __restrict__ tgt_e)
{
  int row = blockIdx.x, tid = threadIdx.x;
  if (row < S_LEN*BATCH) {
    int id = src_ids[row];
    src_e[(size_t)row*EMB + tid] = src_emb[(size_t)id*EMB + tid];
  } else {
    int r = row - S_LEN*BATCH;
    int id = tgt_ids[r];
    tgt_e[(size_t)r*EMB + tid] = tgt_emb[(size_t)id*EMB + tid];
  }
}

// ---------------- generic fp32 GEMM: C = A @ W^T (+bias) ----------------
// BM=32, BN=256, BK=16, 256 threads, micro-tile 4x8.
// rev!=0: A-row remap (reversed-sequence enc projection), needs gridDim.y==40.
__global__ __launch_bounds__(256) void k_gemm(
    const float* __restrict__ A, const float* __restrict__ W,
    const float* __restrict__ bias, float* __restrict__ C,
    int N, int K, int ldw, int rev)
{
  __shared__ float As[16][36];
  __shared__ float Ws[16][256];
  const int tid = threadIdx.x;
  const int tx = tid & 31, ty = tid >> 5;
  const int bn = (int)blockIdx.x << 8;
  const int bmi = (int)blockIdx.y;
  const int bm = bmi << 5;
  const int arow0 = rev ? ((S_LEN - 1 - bmi) << 5) : bm;

  float acc[4][8];
#pragma unroll
  for (int i = 0; i < 4; i++)
#pragma unroll
    for (int j = 0; j < 8; j++) acc[i][j] = 0.f;

  const int ml = tid >> 3, kl = (tid & 7) << 1;
  const float* aptr = A + (size_t)(arow0 + ml)*K + kl;
  const float* wptr = W + (size_t)(bn + tid)*ldw;

  for (int k0 = 0; k0 < K; k0 += 16) {
    const float2 av  = *(const float2*)(aptr + k0);
    const float4 w0v = *(const float4*)(wptr + k0);
    const float4 w1v = *(const float4*)(wptr + k0 + 4);
    const float4 w2v = *(const float4*)(wptr + k0 + 8);
    const float4 w3v = *(const float4*)(wptr + k0 + 12);
    __syncthreads();
    As[kl][ml]   = av.x;
    As[kl+1][ml] = av.y;
    const float wt[16] = {w0v.x,w0v.y,w0v.z,w0v.w, w1v.x,w1v.y,w1v.z,w1v.w,
                          w2v.x,w2v.y,w2v.z,w2v.w, w3v.x,w3v.y,w3v.z,w3v.w};
#pragma unroll
    for (int kk = 0; kk < 16; kk++) Ws[kk][tid] = wt[kk];
    __syncthreads();
#pragma unroll
    for (int kk = 0; kk < 16; kk++) {
      const float4 a4 = *(const float4*)&As[kk][ty << 2];
      const float4 b0 = *(const float4*)&Ws[kk][tx << 2];
      const float4 b1 = *(const float4*)&Ws[kk][128 + (tx << 2)];
      const float ar[4] = {a4.x, a4.y, a4.z, a4.w};
      const float br[8] = {b0.x, b0.y, b0.z, b0.w, b1.x, b1.y, b1.z, b1.w};
#pragma unroll
      for (int i = 0; i < 4; i++)
#pragma unroll
        for (int j = 0; j < 8; j++) acc[i][j] += ar[i]*br[j];
    }
  }
  float4 bb0 = {0,0,0,0}, bb1 = {0,0,0,0};
  if (bias) {
    bb0 = *(const float4*)&bias[bn + (tx << 2)];
    bb1 = *(const float4*)&bias[bn + 128 + (tx << 2)];
  }
#pragma unroll
  for (int i = 0; i < 4; i++) {
    const int row = bm + (ty << 2) + i;
    float4 o0 = {acc[i][0]+bb0.x, acc[i][1]+bb0.y, acc[i][2]+bb0.z, acc[i][3]+bb0.w};
    float4 o1 = {acc[i][4]+bb1.x, acc[i][5]+bb1.y, acc[i][6]+bb1.z, acc[i][7]+bb1.w};
    *(float4*)&C[(size_t)row*N + bn + (tx << 2)] = o0;
    *(float4*)&C[(size_t)row*N + bn + 128 + (tx << 2)] = o1;
  }
}

// ---------------- encoder: one block per (dir, batch) chain, no inter-block sync --------
// 64 blocks x 256 threads. Thread owns units {tid, tid+256}: c in registers,
// h in LDS (broadcast reads), weights streamed from L2/L3.
// Writes enc_hidden (B,S,2H) directly (bwd chain un-reverses), plus hcat/ccat at t=39.
__global__ __launch_bounds__(256) void k_enc(
    const float* __restrict__ xpf, const float* __restrict__ xpb,
    const float* __restrict__ Whf, const float* __restrict__ Whb,
    float* __restrict__ ench, float* __restrict__ hcat, float* __restrict__ ccat)
{
  __shared__ float hl[HID];
  const int blk = blockIdx.x;
  const int dir = blk >> 5, b = blk & 31;
  const int tid = threadIdx.x;
  const float* xp  = dir ? xpb : xpf;
  const float* Whh = dir ? Whb : Whf;

  const float* wp[8];
#pragma unroll
  for (int u = 0; u < 2; u++)
#pragma unroll
    for (int g = 0; g < 4; g++)
      wp[u*4+g] = Whh + (size_t)(g*HID + tid + u*256)*HID;

  float creg[2] = {0.f, 0.f};
  for (int t = 0; t < S_LEN; t++) {
    float a8[8] = {0,0,0,0,0,0,0,0};
    if (t > 0) {
      for (int k = 0; k < HID; k += 4) {
        const float4 hv = *(const float4*)&hl[k];
#pragma unroll
        for (int p = 0; p < 8; p++) {
          const float4 w4 = *(const float4*)(wp[p] + k);
          a8[p] += w4.x*hv.x + w4.y*hv.y + w4.z*hv.z + w4.w*hv.w;
        }
      }
    }
    const float* xrow = xp + (size_t)(t*BATCH + b)*G4H;
    const int s = dir ? (S_LEN-1-t) : t;
    float hn2[2];
#pragma unroll
    for (int u = 0; u < 2; u++) {
      const int j = tid + u*256;
      const float gi = a8[u*4+0] + xrow[j];
      const float gf = a8[u*4+1] + xrow[HID + j];
      const float gg = a8[u*4+2] + xrow[2*HID + j];
      const float go = a8[u*4+3] + xrow[3*HID + j];
      const float cn = sigf(gf)*creg[u] + sigf(gi)*tanhf(gg);
      const float hn = sigf(go)*tanhf(cn);
      creg[u] = cn; hn2[u] = hn;
      ench[((size_t)b*S_LEN + s)*1024 + dir*HID + j] = hn;
    }
    __syncthreads();                       // all reads of hl done
    hl[tid] = hn2[0]; hl[tid+256] = hn2[1];
    __syncthreads();
    if (t == S_LEN-1) {
#pragma unroll
      for (int u = 0; u < 2; u++) {
        const int j = tid + u*256;
        hcat[b*1024 + dir*HID + j] = hn2[u];
        ccat[b*1024 + dir*HID + j] = creg[u];
      }
    }
  }
}

// ---------------- decoder: one block per batch element, no inter-block sync ----------
// 32 blocks x 256 threads. Per step: LSTM gates (thread owns 2 units, K=1024 from
// LDS xa=[o_prev|h]) -> cell -> attention (wave-split scores, softmax, ctx) ->
// combine -> o_t back into xa + bf16 row for the vocab GEMM.
__global__ __launch_bounds__(256) void k_dec(
    const float* __restrict__ xproj, const float* __restrict__ Wih, const float* __restrict__ Whh,
    const float* __restrict__ Wcomb, const float* __restrict__ encp, const float* __restrict__ ench,
    const float* __restrict__ masks, const float* __restrict__ h0, const float* __restrict__ c0,
    unsigned short* __restrict__ obf)
{
  __shared__ float xa[1024];     // [0,512)=o_prev, [512,1024)=h
  __shared__ float ctx[1024];
  __shared__ float scr[S_LEN], sc2[S_LEN];
  const int b = blockIdx.x, tid = threadIdx.x;
  const int l = tid & 63, wv = tid >> 6;

  const float* wihp[8]; const float* whhp[8];
#pragma unroll
  for (int u = 0; u < 2; u++)
#pragma unroll
    for (int g = 0; g < 4; g++) {
      const int row = g*HID + tid + u*256;
      wihp[u*4+g] = Wih + (size_t)row*768 + 256;   // cols 256..767 = o_prev part
      whhp[u*4+g] = Whh + (size_t)row*HID;
    }
  const float* wcp[2] = { Wcomb + (size_t)tid*1536, Wcomb + (size_t)(tid+256)*1536 };

  float creg[2] = { c0[b*HID + tid], c0[b*HID + tid + 256] };
  xa[tid] = 0.f; xa[tid+256] = 0.f;                       // o_{-1} = 0
  xa[512 + tid] = h0[b*HID + tid];
  xa[512 + tid + 256] = h0[b*HID + tid + 256];
  __syncthreads();

  for (int t = 0; t < NDEC; t++) {
    // ---- A: LSTM gates ----
    float a8[8] = {0,0,0,0,0,0,0,0};
    for (int k = 0; k < HID; k += 4) {
      const float4 xv = *(const float4*)&xa[k];
#pragma unroll
      for (int p = 0; p < 8; p++) {
        const float4 w4 = *(const float4*)(wihp[p] + k);
        a8[p] += w4.x*xv.x + w4.y*xv.y + w4.z*xv.z + w4.w*xv.w;
      }
    }
    for (int k = 0; k < HID; k += 4) {
      const float4 xv = *(const float4*)&xa[512 + k];
#pragma unroll
      for (int p = 0; p < 8; p++) {
        const float4 w4 = *(const float4*)(whhp[p] + k);
        a8[p] += w4.x*xv.x + w4.y*xv.y + w4.z*xv.z + w4.w*xv.w;
      }
    }
    const float* xrow = xproj + (size_t)(t*BATCH + b)*G4H;
    float hn2[2];
#pragma unroll
    for (int u = 0; u < 2; u++) {
      const int j = tid + u*256;
      const float gi = a8[u*4+0] + xrow[j];
      const float gf = a8[u*4+1] + xrow[HID + j];
      const float gg = a8[u*4+2] + xrow[2*HID + j];
      const float go = a8[u*4+3] + xrow[3*HID + j];
      const float cn = sigf(gf)*creg[u] + sigf(gi)*tanhf(gg);
      const float hn = sigf(go)*tanhf(cn);
      creg[u] = cn; hn2[u] = hn;
    }
    __syncthreads();                       // all reads of xa done
    xa[512 + tid] = hn2[0]; xa[512 + tid + 256] = hn2[1];
    __syncthreads();

    // ---- B: attention ----
    for (int s = wv; s < S_LEN; s += 4) {
      const float* ep = encp + ((size_t)b*S_LEN + s)*HID;
      float part = 0.f;
#pragma unroll
      for (int kk = 0; kk < 8; kk++) part += ep[l + (kk << 6)] * xa[512 + l + (kk << 6)];
#pragma unroll
      for (int m = 32; m >= 1; m >>= 1) part += __shfl_xor(part, m, 64);
      if (l == 0) scr[s] = (masks[b*S_LEN + s] > 0.f) ? -INFINITY : part;
    }
    __syncthreads();
    {
      float mx = -INFINITY;
      for (int s = 0; s < S_LEN; s++) mx = fmaxf(mx, scr[s]);
      float sm = 0.f;
      for (int s = 0; s < S_LEN; s++) sm += expf(scr[s] - mx);
      const float inv = 1.f/sm;
      if (tid < S_LEN) sc2[tid] = expf(scr[tid] - mx)*inv;
    }
    __syncthreads();
#pragma unroll
    for (int q = 0; q < 4; q++) {
      const int d = tid + (q << 8);
      float cd = 0.f;
      for (int s = 0; s < S_LEN; s++) cd += sc2[s]*ench[((size_t)b*S_LEN + s)*1024 + d];
      ctx[d] = cd;
    }
    __syncthreads();

    // ---- C: combine o_t = tanh([h|ctx] @ W_comb^T) ----
#pragma unroll
    for (int u = 0; u < 2; u++) {
      const float* wr = wcp[u];
      float a = 0.f;
      for (int k = 0; k < HID; k += 4) {
        const float4 w4 = *(const float4*)(wr + k);
        const float4 h4 = *(const float4*)&xa[512 + k];
        a += w4.x*h4.x + w4.y*h4.y + w4.z*h4.z + w4.w*h4.w;
      }
      for (int k = 0; k < 1024; k += 4) {
        const float4 w4 = *(const float4*)(wr + HID + k);
        const float4 c4 = *(const float4*)&ctx[k];
        a += w4.x*c4.x + w4.y*c4.y + w4.z*c4.z + w4.w*c4.w;
      }
      const float o = tanhf(a);
      const int j = tid + u*256;
      xa[j] = o;                                          // next step's o_prev
      obf[(size_t)(t*BATCH + b)*HID + j] = f2bf(o);       // vocab GEMM input (bf16)
    }
    __syncthreads();
  }
}

// ---------------- zero bf16 pad rows 1248..1279 ----------------
__global__ __launch_bounds__(256) void k_zero_bf(unsigned short* __restrict__ p) {
  p[(size_t)MROWS*HID + blockIdx.x*256 + threadIdx.x] = 0;
}

// ---------------- vocab GEMM (bf16 MFMA 16x16x32) + fused log-softmax partials -------
// C[m][v] = sum_k A[m][k]*W[v][k]; A = outs_bf (MPAD x 512 bf16), W fp32 converted
// on the fly (v_perm truncation). BM=128, BN=256, K=512. grid (196, 10), 4 waves.
// A staged in LDS in FRAGMENT order (conflict-free b128 write+read). Epilogue via
// LDS C-tile: per-row chunk max / exp-sum -> pmax/psum; picked logit for tgt col.
__global__ __launch_bounds__(256) void k_vocab(
    const unsigned short* __restrict__ Ab, const float* __restrict__ Wv,
    const int* __restrict__ ptgt,
    float* __restrict__ pmax, float* __restrict__ psum, float* __restrict__ picked)
{
  __shared__ char ldsbuf[133120];                 // Af (131072 B) then reused as Cs (133120 B)
  __shared__ float redm[2][128], reds[2][128];
  short* Af = (short*)ldsbuf;
  float* Cs = (float*)ldsbuf;

  const int tid = threadIdx.x;
  const int l = tid & 63, wq = tid >> 6;
  const int bx = (int)blockIdx.x, bm = (int)blockIdx.y << 7;
  const int bn = bx << 8;

  // ---- stage A-tile (128 x 512 bf16) into fragment-ordered LDS ----
  // frag f = mt*16+ks; lane ln holds A[bm + mt*16 + (ln&15)][ks*32 + (ln>>4)*8 .. +7]
#pragma unroll
  for (int i = 0; i < 32; i++) {
    const int s = tid + (i << 8);
    const int f = s >> 6, ln = s & 63;
    const int row = ((f >> 4) << 4) + (ln & 15);
    const int koff = ((f & 15) << 5) + ((ln >> 4) << 3);
    *(short8v*)&Af[s*8] = *(const short8v*)&Ab[(size_t)(bm + row)*HID + koff];
  }
  __syncthreads();

  // ---- B row pointers (wave wq covers cols wq*64 .. +63) ----
  const float* bptr[4];
#pragma unroll
  for (int nt = 0; nt < 4; nt++) {
    int rowv = bn + wq*64 + nt*16 + (l & 15);
    if (rowv > NVOC-1) rowv = NVOC-1;             // tail clamp; masked in epilogue
    bptr[nt] = Wv + (size_t)rowv*HID + ((l >> 4) << 3);
  }

  f32x4 acc[8][4];
#pragma unroll
  for (int mt = 0; mt < 8; mt++)
#pragma unroll
    for (int nt = 0; nt < 4; nt++) acc[mt][nt] = (f32x4){0.f,0.f,0.f,0.f};

  for (int ks = 0; ks < 16; ks++) {
    short8v bfr[4];
#pragma unroll
    for (int nt = 0; nt < 4; nt++) {
      const float4 wa = *(const float4*)(bptr[nt] + ks*32);
      const float4 wb = *(const float4*)(bptr[nt] + ks*32 + 4);
      union { int i[4]; short8v s; } u;
      u.i[0] = __builtin_amdgcn_perm(__float_as_uint(wa.y), __float_as_uint(wa.x), 0x07060302);
      u.i[1] = __builtin_amdgcn_perm(__float_as_uint(wa.w), __float_as_uint(wa.z), 0x07060302);
      u.i[2] = __builtin_amdgcn_perm(__float_as_uint(wb.y), __float_as_uint(wb.x), 0x07060302);
      u.i[3] = __builtin_amdgcn_perm(__float_as_uint(wb.w), __float_as_uint(wb.z), 0x07060302);
      bfr[nt] = u.s;
    }
#pragma unroll
    for (int mt = 0; mt < 8; mt++) {
      const short8v af = *(const short8v*)&Af[((mt*16 + ks)*64 + l)*8];
#pragma unroll
      for (int nt = 0; nt < 4; nt++)
        acc[mt][nt] = __builtin_amdgcn_mfma_f32_16x16x32_bf16(af, bfr[nt], acc[mt][nt], 0, 0, 0);
    }
  }

  __syncthreads();                                // Af reads done; reuse as Cs
  // C/D layout (m89-verified): row=(lane>>4)*4+reg, col=lane&15
#pragma unroll
  for (int mt = 0; mt < 8; mt++)
#pragma unroll
    for (int nt = 0; nt < 4; nt++) {
      const int row = mt*16 + (l >> 4)*4;
      const int col = wq*64 + nt*16 + (l & 15);
#pragma unroll
      for (int r = 0; r < 4; r++)
        Cs[(row + r)*260 + col] = acc[mt][nt][r];
    }
  __syncthreads();

  // ---- per-row chunk max / exp-sum over 256 cols (2 threads per row) ----
  const int row = tid & 127, half = tid >> 7;
  const float* crow = Cs + row*260 + half*128;
  const int colbase = bn + half*128;
  float mx = -INFINITY;
  for (int i = 0; i < 128; i++)
    if (colbase + i < NVOC) mx = fmaxf(mx, crow[i]);
  redm[half][row] = mx;
  __syncthreads();
  const float rmx = fmaxf(redm[0][row], redm[1][row]);
  float sm = 0.f;
  for (int i = 0; i < 128; i++)
    if (colbase + i < NVOC) sm += expf(crow[i] - rmx);
  reds[half][row] = sm;
  __syncthreads();
  if (half == 0) {
    const int rowg = bm + row;
    pmax[(size_t)rowg*NCHUNK + bx] = rmx;
    psum[(size_t)rowg*NCHUNK + bx] = reds[0][row] + reds[1][row];
    if (rowg < MROWS) {
      const int tv = ptgt[((rowg >> 5) + 1)*BATCH + (rowg & 31)];
      const int rel = tv - bn;
      if (rel >= 0 && rel < 256) picked[rowg] = Cs[row*260 + rel];
    }
  }
}

// ---------------- final reduce: per b, sum_t (picked - lse) * (tgt != 0) ----------------
__global__ __launch_bounds__(256) void k_final(
    const float* __restrict__ pmax, const float* __restrict__ psum,
    const float* __restrict__ picked, const int* __restrict__ ptgt,
    float* __restrict__ out)
{
  __shared__ float red[8];
  const int b = (int)blockIdx.x, tid = threadIdx.x;
  const int lane = tid & 63, w = tid >> 6;
  float accum = 0.f;
  for (int t = 0; t < NDEC; t++) {
    const int row = t*BATCH + b;
    const float* pm = pmax + (size_t)row*NCHUNK;
    const float* ps = psum + (size_t)row*NCHUNK;
    float mx = -INFINITY;
    for (int c = tid; c < NCHUNK; c += 256) mx = fmaxf(mx, pm[c]);
#pragma unroll
    for (int m = 32; m >= 1; m >>= 1) mx = fmaxf(mx, __shfl_xor(mx, m, 64));
    if (lane == 0) red[w] = mx;
    __syncthreads();
    mx = fmaxf(fmaxf(red[0], red[1]), fmaxf(red[2], red[3]));
    __syncthreads();
    float sm = 0.f;
    for (int c = tid; c < NCHUNK; c += 256) sm += ps[c]*expf(pm[c] - mx);
#pragma unroll
    for (int m = 32; m >= 1; m >>= 1) sm += __shfl_xor(sm, m, 64);
    if (lane == 0) red[w] = sm;
    __syncthreads();
    sm = red[0] + red[1] + red[2] + red[3];
    __syncthreads();
    if (tid == 0) {
      const int tv = ptgt[(t + 1)*BATCH + b];
      if (tv != 0) accum += picked[row] - (mx + logf(sm));
    }
  }
  if (tid == 0) out[b] = accum;
}

// ---------------- host ----------------
extern "C" void kernel_launch(void* const* d_in, const int* in_sizes, int n_in,
                              void* d_out, int out_size, void* d_ws, size_t ws_size,
                              hipStream_t stream) {
  (void)in_sizes; (void)n_in; (void)out_size; (void)ws_size;
  const int*   p_src     = (const int*)d_in[0];
  const int*   p_tgt     = (const int*)d_in[1];
  const float* enc_masks = (const float*)d_in[2];
  const float* src_embed = (const float*)d_in[3];
  const float* tgt_embed = (const float*)d_in[4];
  const float* Wih_f = (const float*)d_in[5];
  const float* Whh_f = (const float*)d_in[6];
  const float* b_f   = (const float*)d_in[7];
  const float* Wih_b = (const float*)d_in[8];
  const float* Whh_b = (const float*)d_in[9];
  const float* b_b   = (const float*)d_in[10];
  const float* dWih  = (const float*)d_in[11];
  const float* dWhh  = (const float*)d_in[12];
  const float* db    = (const float*)d_in[13];
  const float* W_h   = (const float*)d_in[14];
  const float* W_c   = (const float*)d_in[15];
  const float* W_att = (const float*)d_in[16];
  const float* W_comb= (const float*)d_in[17];
  const float* W_voc = (const float*)d_in[18];
  float* out = (float*)d_out;

  float* p = (float*)d_ws;
  float* src_e    = p; p += S_LEN*BATCH*EMB;
  float* tgt_e    = p; p += NDEC*BATCH*EMB;
  float* xpf      = p; p += S_LEN*BATCH*G4H;
  float* xpb      = p; p += S_LEN*BATCH*G4H;
  float* dec_xp   = p; p += NDEC*BATCH*G4H;
  float* ench     = p; p += BATCH*S_LEN*2*HID;
  float* encp     = p; p += BATCH*S_LEN*HID;
  float* hcat     = p; p += BATCH*2*HID;
  float* ccat     = p; p += BATCH*2*HID;
  float* h0       = p; p += BATCH*HID;
  float* c0       = p; p += BATCH*HID;
  unsigned short* outs_bf = (unsigned short*)p; p += (size_t)MPAD*HID/2;   // bf16
  float* pmaxb    = p; p += (size_t)MPAD*NCHUNK;
  float* psumb    = p; p += (size_t)MPAD*NCHUNK;
  float* pickedb  = p; p += MPAD;

  // embeddings
  k_embed<<<S_LEN*BATCH + NDEC*BATCH, 256, 0, stream>>>(p_src, p_tgt, src_embed, tgt_embed, src_e, tgt_e);

  // batched input projections (bias folded)
  k_gemm<<<dim3(8, 40), 256, 0, stream>>>(src_e, Wih_f, b_f, xpf, G4H, EMB, EMB, 0);
  k_gemm<<<dim3(8, 40), 256, 0, stream>>>(src_e, Wih_b, b_b, xpb, G4H, EMB, EMB, 1);
  k_gemm<<<dim3(8, NDEC), 256, 0, stream>>>(tgt_e, dWih, db, dec_xp, G4H, EMB, 768, 0);

  // bi-LSTM encoder: 64 independent (dir,batch) chains, no inter-block sync
  k_enc<<<64, 256, 0, stream>>>(xpf, xpb, Whh_f, Whh_b, ench, hcat, ccat);

  // enc_proj, decoder init h/c
  k_gemm<<<dim3(2, 40), 256, 0, stream>>>(ench, W_att, nullptr, encp, HID, 2*HID, 2*HID, 0);
  k_gemm<<<dim3(2, 1), 256, 0, stream>>>(hcat, W_h, nullptr, h0, HID, 2*HID, 2*HID, 0);
  k_gemm<<<dim3(2, 1), 256, 0, stream>>>(ccat, W_c, nullptr, c0, HID, 2*HID, 2*HID, 0);

  // decoder: 32 independent batch chains (LSTM + attention + combine)
  k_dec<<<32, 256, 0, stream>>>(dec_xp, dWih, dWhh, W_comb, encp, ench, enc_masks, h0, c0, outs_bf);

  // vocab projection (bf16 MFMA) + fused log-softmax partials
  k_zero_bf<<<(MPAD-MROWS)*HID/256, 256, 0, stream>>>(outs_bf);
  k_vocab<<<dim3(NCHUNK, MPAD/128), 256, 0, stream>>>(outs_bf, W_voc, p_tgt, pmaxb, psumb, pickedb);
  k_final<<<32, 256, 0, stream>>>(pmaxb, psumb, pickedb, p_tgt, out);
}